// Round 5
// baseline (609.995 us; speedup 1.0000x reference)
//
#include <hip/hip_runtime.h>

// MGDPR: B=2 R=5 N=1024 E=3 L=2, D=64; IN_RET=320 INTER=256 OUT_RET=256
// H1=128 H_RET=320 N_CLS=2; D_gamma strictly-lower = 0.4. All fp32.
#define NB 2
#define NR 5
#define NN_ 1024
#define NL 2
#define MSPLIT 4

// ---- init: skip[b,n,r*64+f] = x[b,r,n,f] (float4) ----
__global__ void init_kernel(const float* __restrict__ x, float* __restrict__ skip) {
    int idx = blockIdx.x * 256 + threadIdx.x;      // 163840 float4s
    int d4 = idx & 15;
    int n = (idx >> 4) & 1023;
    int br = idx >> 14;
    int b = br / NR, r = br % NR;
    float4 v = ((const float4*)x)[idx];
    *(float4*)(skip + ((size_t)b * NN_ + n) * 320 + r * 64 + d4 * 4) = v;
}

// ---- feats partial: part[mz][br][n][d] = sum_{m chunk} (Σe θ·T)·a·h ----
__global__ __launch_bounds__(256) void feats_kernel(
    const float* __restrict__ T, const float* __restrict__ theta,
    const float* __restrict__ a, const float* __restrict__ h,
    float* __restrict__ part, int l) {
    __shared__ float As[32][68];   // wt k-major: As[m][n]
    __shared__ float Ws[32][68];   // hs: Ws[m][d]
    int br = blockIdx.y;
    int b = br / NR, r = br % NR;
    int n0 = blockIdx.x * 64;
    int mz = blockIdx.z;
    int tid = threadIdx.x;
    int tx = tid & 15, ty = tid >> 4;
    const float* Tb = T + (size_t)(l * NR + r) * 3145728;
    float th0 = theta[(l * NR + r) * 3 + 0];
    float th1 = theta[(l * NR + r) * 3 + 1];
    float th2 = theta[(l * NR + r) * 3 + 2];
    const float* ab = a + (size_t)(b * NR + r) * 1048576;
    const float* hb = h + (size_t)(b * NR + r) * 65536;
    int mbeg = mz * (NN_ / MSPLIT), mend = mbeg + NN_ / MSPLIT;
    int c4 = tid & 7, nrow = tid >> 3;      // wt staging
    int d4 = tid & 15, mrow = tid >> 4;     // hs staging
    float4 pT0[2], pT1[2], pT2[2], pA[2], pH[2];
    auto LOAD = [&](int k0) {
#pragma unroll
        for (int j = 0; j < 2; ++j) {
            size_t o = (size_t)(n0 + nrow + j * 32) * 1024 + k0 + c4 * 4;
            pT0[j] = *(const float4*)(Tb + o);
            pT1[j] = *(const float4*)(Tb + 1048576 + o);
            pT2[j] = *(const float4*)(Tb + 2097152 + o);
            pA[j]  = *(const float4*)(ab + o);
        }
#pragma unroll
        for (int j = 0; j < 2; ++j)
            pH[j] = *(const float4*)(hb + (size_t)(k0 + mrow + j * 16) * 64 + d4 * 4);
    };
    float acc[4][4] = {};
    LOAD(mbeg);
    for (int k0 = mbeg; k0 < mend; k0 += 32) {
        float4 w4[2];
#pragma unroll
        for (int j = 0; j < 2; ++j) {
            w4[j].x = (th0 * pT0[j].x + th1 * pT1[j].x + th2 * pT2[j].x) * pA[j].x;
            w4[j].y = (th0 * pT0[j].y + th1 * pT1[j].y + th2 * pT2[j].y) * pA[j].y;
            w4[j].z = (th0 * pT0[j].z + th1 * pT1[j].z + th2 * pT2[j].z) * pA[j].z;
            w4[j].w = (th0 * pT0[j].w + th1 * pT1[j].w + th2 * pT2[j].w) * pA[j].w;
        }
        __syncthreads();
#pragma unroll
        for (int j = 0; j < 2; ++j) {
            int n = nrow + j * 32;
            As[c4 * 4 + 0][n] = w4[j].x; As[c4 * 4 + 1][n] = w4[j].y;
            As[c4 * 4 + 2][n] = w4[j].z; As[c4 * 4 + 3][n] = w4[j].w;
        }
#pragma unroll
        for (int j = 0; j < 2; ++j)
            *(float4*)&Ws[mrow + j * 16][d4 * 4] = pH[j];
        if (k0 + 32 < mend) LOAD(k0 + 32);
        __syncthreads();
#pragma unroll
        for (int kk = 0; kk < 32; ++kk) {
            float4 ra = *(const float4*)&As[kk][ty * 4];
            float4 rw = *(const float4*)&Ws[kk][tx * 4];
            float ar[4] = {ra.x, ra.y, ra.z, ra.w};
            float wr[4] = {rw.x, rw.y, rw.z, rw.w};
#pragma unroll
            for (int i = 0; i < 4; ++i)
#pragma unroll
                for (int j = 0; j < 4; ++j) acc[i][j] += ar[i] * wr[j];
        }
    }
    float* pb = part + ((size_t)mz * 10 + br) * 65536;
#pragma unroll
    for (int i = 0; i < 4; ++i) {
        float4 o4 = make_float4(acc[i][0], acc[i][1], acc[i][2], acc[i][3]);
        *(float4*)(pb + (size_t)(n0 + ty * 4 + i) * 64 + tx * 4) = o4;
    }
}

// ---- fused: feats = Σz part[z]; diff = prelu(feats @ fc_w[l,r]^T + fc_b, a0) ----
__global__ __launch_bounds__(256) void reduce_fc_kernel(
    const float* __restrict__ part, const float* __restrict__ fc_w,
    const float* __restrict__ fc_b, const float* __restrict__ a0,
    float* __restrict__ diff, int l) {
    __shared__ float F[64][68];
    __shared__ float Wl[64][68];
    int br = blockIdx.y;
    int r = br % NR;
    int n0 = blockIdx.x * 64;
    int tid = threadIdx.x;
    int lane = tid & 63, g = tid >> 6;
#pragma unroll
    for (int j = 0; j < 4; ++j) {
        int d4 = g + j * 4;
        size_t off = (size_t)br * 65536 + (size_t)(n0 + lane) * 64 + d4 * 4;
        float4 s = *(const float4*)(part + off);
#pragma unroll
        for (int z = 1; z < MSPLIT; ++z) {
            float4 p = *(const float4*)(part + (size_t)z * 655360 + off);
            s.x += p.x; s.y += p.y; s.z += p.z; s.w += p.w;
        }
        F[d4 * 4 + 0][lane] = s.x; F[d4 * 4 + 1][lane] = s.y;
        F[d4 * 4 + 2][lane] = s.z; F[d4 * 4 + 3][lane] = s.w;
    }
    const float* w = fc_w + (size_t)(l * NR + r) * 4096;
#pragma unroll
    for (int j = 0; j < 4; ++j) {
        int d4 = g + j * 4;
        float4 wv = *(const float4*)(w + (size_t)lane * 64 + d4 * 4);
        Wl[d4 * 4 + 0][lane] = wv.x; Wl[d4 * 4 + 1][lane] = wv.y;
        Wl[d4 * 4 + 2][lane] = wv.z; Wl[d4 * 4 + 3][lane] = wv.w;
    }
    __syncthreads();
    int tx = tid & 15, ty = tid >> 4;
    float acc[4][4] = {};
#pragma unroll
    for (int kk = 0; kk < 64; ++kk) {
        float4 ra = *(const float4*)&F[kk][ty * 4];
        float4 rw = *(const float4*)&Wl[kk][tx * 4];
        float ar[4] = {ra.x, ra.y, ra.z, ra.w};
        float wr[4] = {rw.x, rw.y, rw.z, rw.w};
#pragma unroll
        for (int i = 0; i < 4; ++i)
#pragma unroll
            for (int j = 0; j < 4; ++j) acc[i][j] += ar[i] * wr[j];
    }
    float al = a0[l];
    const float* bia = fc_b + (l * NR + r) * 64;
#pragma unroll
    for (int i = 0; i < 4; ++i) {
        float4 o4;
        float* op = &o4.x;
#pragma unroll
        for (int j = 0; j < 4; ++j) {
            float v = acc[i][j] + bia[tx * 4 + j];
            op[j] = (v >= 0.f) ? v : al * v;
        }
        *(float4*)(diff + (size_t)br * 65536 + (size_t)(n0 + ty * 4 + i) * 64 + tx * 4) = o4;
    }
}

// ---- u[b,s,:,:] = prelu(sum_r cw*diff[b,r] + cb, a1) (float4) ----
__global__ void conv_kernel(const float* __restrict__ diff,
                            const float* __restrict__ cw, const float* __restrict__ cb,
                            const float* __restrict__ a1, float* __restrict__ u, int l) {
    int idx = blockIdx.x * 256 + threadIdx.x;
    int no4 = idx & 16383;
    int bs = idx >> 14;
    int s = bs % NR, b = bs / NR;
    const float* dbase = diff + (size_t)b * NR * 65536;
    float bias = cb[l * NR + s];
    float4 acc = make_float4(bias, bias, bias, bias);
#pragma unroll
    for (int r = 0; r < NR; ++r) {
        float w = cw[(l * NR + s) * NR + r];
        float4 dv = *(const float4*)(dbase + (size_t)r * 65536 + no4 * 4);
        acc.x += w * dv.x; acc.y += w * dv.y; acc.z += w * dv.z; acc.w += w * dv.w;
    }
    float al = a1[l];
    acc.x = acc.x >= 0.f ? acc.x : al * acc.x;
    acc.y = acc.y >= 0.f ? acc.y : al * acc.y;
    acc.z = acc.z >= 0.f ? acc.z : al * acc.z;
    acc.w = acc.w >= 0.f ? acc.w : al * acc.w;
    *(float4*)(u + (size_t)bs * 65536 + no4 * 4) = acc;
}

// ---- batched GEMM, BK=64, per-entry params, optional 2-partial A sum ----
struct BEnt {
    const float* A; const float* A2; const float* W; const float* bias;
    const float* alpha; float* C;
    int lda, Kcap, Nw, ldc, w_nn, tri, trik, kbeg;
};
struct BArg { BEnt e[4]; };

__global__ __launch_bounds__(256) void gemm_kernel(BArg bp) {
    BEnt E = bp.e[blockIdx.z];
    int m0 = blockIdx.y * 64, n0 = blockIdx.x * 64;
    if (n0 >= E.Nw) return;
    if (E.tri && (m0 + 63 <= n0)) return;
    int kend = E.trik ? min(E.Kcap, m0 + 64) : E.Kcap;
    __shared__ float As[64][68];
    __shared__ float Ws[64][68];
    int tid = threadIdx.x;
    int tx = tid & 15, ty = tid >> 4;
    int ar = tid & 63, acg = tid >> 6;      // NT row-fast: lane=row, wave=k-chunk
    int wr = tid >> 4, wc = tid & 15;       // NN col-fast
    const float* Ap = E.A; const float* Ap2 = E.A2; const float* Wp = E.W;
    int lda = E.lda, Kc = E.Kcap, Nw = E.Nw, wnn = E.w_nn;
    float acc[4][4] = {};
    float4 pA[4], pW[4];
    auto LOAD = [&](int k0) {
#pragma unroll
        for (int j = 0; j < 4; ++j) {
            size_t o = (size_t)(m0 + ar) * lda + k0 + (acg * 4 + j) * 4;
            pA[j] = *(const float4*)(Ap + o);
            if (Ap2) {
                float4 t = *(const float4*)(Ap2 + o);
                pA[j].x += t.x; pA[j].y += t.y; pA[j].z += t.z; pA[j].w += t.w;
            }
        }
        if (!wnn) {
#pragma unroll
            for (int j = 0; j < 4; ++j)
                pW[j] = *(const float4*)(Wp + (size_t)(n0 + ar) * Kc + k0 + (acg * 4 + j) * 4);
        } else {
#pragma unroll
            for (int j = 0; j < 4; ++j)
                pW[j] = *(const float4*)(Wp + (size_t)(k0 + wr + j * 16) * Nw + n0 + wc * 4);
        }
    };
    if (E.kbeg < kend) {
        LOAD(E.kbeg);
        for (int k0 = E.kbeg; k0 < kend; k0 += 64) {
            __syncthreads();
#pragma unroll
            for (int j = 0; j < 4; ++j) {       // A transpose-stage, conflict-free
                int kb = (acg * 4 + j) * 4;
                As[kb + 0][ar] = pA[j].x; As[kb + 1][ar] = pA[j].y;
                As[kb + 2][ar] = pA[j].z; As[kb + 3][ar] = pA[j].w;
            }
            if (!wnn) {
#pragma unroll
                for (int j = 0; j < 4; ++j) {
                    int kb = (acg * 4 + j) * 4;
                    Ws[kb + 0][ar] = pW[j].x; Ws[kb + 1][ar] = pW[j].y;
                    Ws[kb + 2][ar] = pW[j].z; Ws[kb + 3][ar] = pW[j].w;
                }
            } else {
#pragma unroll
                for (int j = 0; j < 4; ++j)
                    *(float4*)&Ws[wr + j * 16][wc * 4] = pW[j];
            }
            if (k0 + 64 < kend) LOAD(k0 + 64);
            __syncthreads();
#pragma unroll
            for (int kk = 0; kk < 64; ++kk) {
                float4 ra = *(const float4*)&As[kk][ty * 4];
                float4 rw = *(const float4*)&Ws[kk][tx * 4];
                float arr[4] = {ra.x, ra.y, ra.z, ra.w};
                float wrr[4] = {rw.x, rw.y, rw.z, rw.w};
#pragma unroll
                for (int i = 0; i < 4; ++i)
#pragma unroll
                    for (int j = 0; j < 4; ++j) acc[i][j] += arr[i] * wrr[j];
            }
        }
    }
    float al = E.alpha ? *E.alpha : 0.f;
#pragma unroll
    for (int i = 0; i < 4; ++i) {
        int m = m0 + ty * 4 + i;
        float4 o4;
        float* op = &o4.x;
#pragma unroll
        for (int j = 0; j < 4; ++j) {
            int n = n0 + tx * 4 + j;
            float v = acc[i][j];
            if (E.bias) v += E.bias[n];
            if (E.tri) v = (m > n) ? 0.4f * v : 0.f;
            if (E.alpha) v = (v >= 0.f) ? v : al * v;
            op[j] = v;
        }
        *(float4*)(E.C + (size_t)m * E.ldc + n0 + tx * 4) = o4;
    }
}

// ---- final: out[m,c] = out1[m,:] @ mlp2_w[c,:] + mlp2_b[c] ----
__global__ void final_kernel(const float* __restrict__ out1,
                             const float* __restrict__ w2, const float* __restrict__ b2,
                             float* __restrict__ out) {
    int idx = blockIdx.x * 256 + threadIdx.x;
    if (idx >= 2048 * 2) return;
    int m = idx >> 1, c = idx & 1;
    float acc = b2[c];
    const float* row = out1 + (size_t)m * 128;
#pragma unroll 8
    for (int dd = 0; dd < 128; ++dd) acc += row[dd] * w2[c * 128 + dd];
    out[idx] = acc;
}

extern "C" void kernel_launch(void* const* d_in, const int* in_sizes, int n_in,
                              void* d_out, int out_size, void* d_ws, size_t ws_size,
                              hipStream_t stream) {
    auto fp = [&](int i) { return (const float*)d_in[i]; };
    const float *x = fp(0), *a = fp(1), *T = fp(2), *theta = fp(3),
        *fc_w = fp(4), *fc_b = fp(5), *conv_w = fp(6), *conv_b = fp(7),
        *a0 = fp(8), *a1 = fp(9), *qw = fp(10), *qb = fp(11), *kw = fp(12), *kb = fp(13),
        *vw = fp(14), *vb = fp(15), *rw = fp(16), *rb = fp(17), *a_ret = fp(18),
        *l1_w = fp(19), *l1_b = fp(20), *l2_w = fp(21), *l2_b = fp(22),
        *m1w = fp(23), *m1b = fp(24), *m2w = fp(25), *m2b = fp(26), *a_mlp = fp(27);

    float* ws = (float*)d_ws;
    float* part = ws;   ws += MSPLIT * 655360;  // 10.5 MB; dead after reduce_fc
    float* scores = part;                        // alias: [B,N,N] 8.4 MB <= part
    float* u0 = ws;     ws += 655360;
    float* u1 = ws;     ws += 655360;
    float* skip = ws;   ws += 655360;
    float* diff = ws;   ws += 655360;
    float* q = ws;      ws += 524288;
    float* kk = ws;     ws += 524288;
    float* v = ws;      ws += 524288;
    float* retP0 = ws;  ws += 524288;           // ret split-K partial 0
    float* retP1 = ws;  ws += 524288;           // ret split-K partial 1
    float* cat = ws;    ws += 786432;           // [B,N,384] = [eta | ts]
    float* out1 = ws;   ws += 262144;           // total ~36 MB

    init_kernel<<<640, 256, 0, stream>>>(x, skip);
    for (int l = 0; l < NL; ++l) {
        const float* h = (l == 0) ? x : u0;
        float* u = (l == 0) ? u0 : u1;
        feats_kernel<<<dim3(16, 10, MSPLIT), 256, 0, stream>>>(T, theta, a, h, part, l);
        reduce_fc_kernel<<<dim3(16, 10), 256, 0, stream>>>(part, fc_w, fc_b, a0, diff, l);
        conv_kernel<<<640, 256, 0, stream>>>(diff, conv_w, conv_b, a1, u, l);
        {   // qkv + ts fused, z=4
            BArg g;
            g.e[0] = {u, nullptr, qw + (size_t)l * 81920, qb + l * 256, nullptr, q, 320, 320, 256, 256, 0, 0, 0, 0};
            g.e[1] = {u, nullptr, kw + (size_t)l * 81920, kb + l * 256, nullptr, kk, 320, 320, 256, 256, 0, 0, 0, 0};
            g.e[2] = {u, nullptr, vw + (size_t)l * 81920, vb + l * 256, nullptr, v, 320, 320, 256, 256, 0, 0, 0, 0};
            g.e[3] = {skip, nullptr, l1_w + (size_t)l * 40960, l1_b + l * 128, nullptr, cat + 256, 320, 320, 128, 384, 0, 0, 0, 0};
            gemm_kernel<<<dim3(4, 32, 4), 256, 0, stream>>>(g);
        }
        {   // scores = tri(q @ k^T), per-batch z=2, upper tiles skipped
            BArg g;
            g.e[0] = {q, nullptr, kk, nullptr, nullptr, scores, 256, 256, 1024, 1024, 0, 1, 0, 0};
            g.e[1] = {q + 262144, nullptr, kk + 262144, nullptr, nullptr, scores + 1048576, 256, 256, 1024, 1024, 0, 1, 0, 0};
            g.e[2] = g.e[0]; g.e[3] = g.e[0];
            gemm_kernel<<<dim3(16, 16, 2), 256, 0, stream>>>(g);
        }
        {   // ret partials: z = b*2+ks, K split at 512, trik clamps to m0+64
            BArg g;
            for (int b = 0; b < 2; ++b)
                for (int ks = 0; ks < 2; ++ks)
                    g.e[b * 2 + ks] = {scores + (size_t)b * 1048576, nullptr, v + (size_t)b * 262144,
                                       nullptr, nullptr, (ks ? retP1 : retP0) + (size_t)b * 262144,
                                       1024, ks ? 1024 : 512, 256, 256, 1, 0, 1, ks ? 512 : 0};
            gemm_kernel<<<dim3(4, 16, 4), 256, 0, stream>>>(g);
        }
        {   // eta -> cat[:,0:256], A = retP0 + retP1, prelu(a_ret)
            BArg g;
            g.e[0] = {retP0, retP1, rw + (size_t)l * 65536, rb + l * 256, a_ret + l, cat, 256, 256, 256, 384, 0, 0, 0, 0};
            g.e[1] = g.e[0]; g.e[2] = g.e[0]; g.e[3] = g.e[0];
            gemm_kernel<<<dim3(4, 32, 1), 256, 0, stream>>>(g);
        }
        {   // skip = cat @ l2_w^T + l2_b
            BArg g;
            g.e[0] = {cat, nullptr, l2_w + (size_t)l * 122880, l2_b + l * 320, nullptr, skip, 384, 384, 320, 320, 0, 0, 0, 0};
            g.e[1] = g.e[0]; g.e[2] = g.e[0]; g.e[3] = g.e[0];
            gemm_kernel<<<dim3(5, 32, 1), 256, 0, stream>>>(g);
        }
    }
    {   // out1 = prelu(skip @ mlp1_w^T + mlp1_b, a_mlp)
        BArg g;
        g.e[0] = {skip, nullptr, m1w, m1b, a_mlp, out1, 320, 320, 128, 128, 0, 0, 0, 0};
        g.e[1] = g.e[0]; g.e[2] = g.e[0]; g.e[3] = g.e[0];
        gemm_kernel<<<dim3(2, 32, 1), 256, 0, stream>>>(g);
    }
    final_kernel<<<16, 256, 0, stream>>>(out1, m2w, m2b, (float*)d_out);
}

// Round 6
// 592.089 us; speedup vs baseline: 1.0302x; 1.0302x over previous
//
#include <hip/hip_runtime.h>

// MGDPR: B=2 R=5 N=1024 E=3 L=2, D=64; IN_RET=320 INTER=256 OUT_RET=256
// H1=128 H_RET=320 N_CLS=2; D_gamma strictly-lower = 0.4. All fp32.
#define NB 2
#define NR 5
#define NN_ 1024
#define NL 2
#define MSPLIT 8

// ---- init: skip[b,n,r*64+f] = x[b,r,n,f] (float4) ----
__global__ void init_kernel(const float* __restrict__ x, float* __restrict__ skip) {
    int idx = blockIdx.x * 256 + threadIdx.x;      // 163840 float4s
    int d4 = idx & 15;
    int n = (idx >> 4) & 1023;
    int br = idx >> 14;
    int b = br / NR, r = br % NR;
    float4 v = ((const float4*)x)[idx];
    *(float4*)(skip + ((size_t)b * NN_ + n) * 320 + r * 64 + d4 * 4) = v;
}

// ---- feats partial: part[mz][br][n][d] = sum_{m chunk} (Σe θ·T)·a·h ----
// 64n x 64d tile, 4x4 register blocking, k(=m)-major LDS, prefetch.
// MSPLIT=8 -> 1280 blocks (5/CU) for latency hiding.
__global__ __launch_bounds__(256) void feats_kernel(
    const float* __restrict__ T, const float* __restrict__ theta,
    const float* __restrict__ a, const float* __restrict__ h,
    float* __restrict__ part, int l) {
    __shared__ float As[32][68];   // wt k-major: As[m][n]
    __shared__ float Ws[32][68];   // hs: Ws[m][d]
    int br = blockIdx.y;
    int b = br / NR, r = br % NR;
    int n0 = blockIdx.x * 64;
    int mz = blockIdx.z;
    int tid = threadIdx.x;
    int tx = tid & 15, ty = tid >> 4;
    const float* Tb = T + (size_t)(l * NR + r) * 3145728;
    float th0 = theta[(l * NR + r) * 3 + 0];
    float th1 = theta[(l * NR + r) * 3 + 1];
    float th2 = theta[(l * NR + r) * 3 + 2];
    const float* ab = a + (size_t)(b * NR + r) * 1048576;
    const float* hb = h + (size_t)(b * NR + r) * 65536;
    int mbeg = mz * (NN_ / MSPLIT), mend = mbeg + NN_ / MSPLIT;
    int c4 = tid & 7, nrow = tid >> 3;      // wt staging
    int d4 = tid & 15, mrow = tid >> 4;     // hs staging
    float4 pT0[2], pT1[2], pT2[2], pA[2], pH[2];
    auto LOAD = [&](int k0) {
#pragma unroll
        for (int j = 0; j < 2; ++j) {
            size_t o = (size_t)(n0 + nrow + j * 32) * 1024 + k0 + c4 * 4;
            pT0[j] = *(const float4*)(Tb + o);
            pT1[j] = *(const float4*)(Tb + 1048576 + o);
            pT2[j] = *(const float4*)(Tb + 2097152 + o);
            pA[j]  = *(const float4*)(ab + o);
        }
#pragma unroll
        for (int j = 0; j < 2; ++j)
            pH[j] = *(const float4*)(hb + (size_t)(k0 + mrow + j * 16) * 64 + d4 * 4);
    };
    float acc[4][4] = {};
    LOAD(mbeg);
    for (int k0 = mbeg; k0 < mend; k0 += 32) {
        float4 w4[2];
#pragma unroll
        for (int j = 0; j < 2; ++j) {
            w4[j].x = (th0 * pT0[j].x + th1 * pT1[j].x + th2 * pT2[j].x) * pA[j].x;
            w4[j].y = (th0 * pT0[j].y + th1 * pT1[j].y + th2 * pT2[j].y) * pA[j].y;
            w4[j].z = (th0 * pT0[j].z + th1 * pT1[j].z + th2 * pT2[j].z) * pA[j].z;
            w4[j].w = (th0 * pT0[j].w + th1 * pT1[j].w + th2 * pT2[j].w) * pA[j].w;
        }
        __syncthreads();
#pragma unroll
        for (int j = 0; j < 2; ++j) {
            int n = nrow + j * 32;
            As[c4 * 4 + 0][n] = w4[j].x; As[c4 * 4 + 1][n] = w4[j].y;
            As[c4 * 4 + 2][n] = w4[j].z; As[c4 * 4 + 3][n] = w4[j].w;
        }
#pragma unroll
        for (int j = 0; j < 2; ++j)
            *(float4*)&Ws[mrow + j * 16][d4 * 4] = pH[j];
        if (k0 + 32 < mend) LOAD(k0 + 32);
        __syncthreads();
#pragma unroll
        for (int kk = 0; kk < 32; ++kk) {
            float4 ra = *(const float4*)&As[kk][ty * 4];
            float4 rw = *(const float4*)&Ws[kk][tx * 4];
            float ar[4] = {ra.x, ra.y, ra.z, ra.w};
            float wr[4] = {rw.x, rw.y, rw.z, rw.w};
#pragma unroll
            for (int i = 0; i < 4; ++i)
#pragma unroll
                for (int j = 0; j < 4; ++j) acc[i][j] += ar[i] * wr[j];
        }
    }
    float* pb = part + ((size_t)mz * 10 + br) * 65536;
#pragma unroll
    for (int i = 0; i < 4; ++i) {
        float4 o4 = make_float4(acc[i][0], acc[i][1], acc[i][2], acc[i][3]);
        *(float4*)(pb + (size_t)(n0 + ty * 4 + i) * 64 + tx * 4) = o4;
    }
}

// ---- fused: feats = Σz part[z]; diff = prelu(feats @ fc_w[l,r]^T + fc_b, a0) ----
__global__ __launch_bounds__(256) void reduce_fc_kernel(
    const float* __restrict__ part, const float* __restrict__ fc_w,
    const float* __restrict__ fc_b, const float* __restrict__ a0,
    float* __restrict__ diff, int l) {
    __shared__ float F[64][68];
    __shared__ float Wl[64][68];
    int br = blockIdx.y;
    int r = br % NR;
    int n0 = blockIdx.x * 64;
    int tid = threadIdx.x;
    int lane = tid & 63, g = tid >> 6;
#pragma unroll
    for (int j = 0; j < 4; ++j) {
        int d4 = g + j * 4;
        size_t off = (size_t)br * 65536 + (size_t)(n0 + lane) * 64 + d4 * 4;
        float4 s = *(const float4*)(part + off);
#pragma unroll
        for (int z = 1; z < MSPLIT; ++z) {
            float4 p = *(const float4*)(part + (size_t)z * 655360 + off);
            s.x += p.x; s.y += p.y; s.z += p.z; s.w += p.w;
        }
        F[d4 * 4 + 0][lane] = s.x; F[d4 * 4 + 1][lane] = s.y;
        F[d4 * 4 + 2][lane] = s.z; F[d4 * 4 + 3][lane] = s.w;
    }
    const float* w = fc_w + (size_t)(l * NR + r) * 4096;
#pragma unroll
    for (int j = 0; j < 4; ++j) {
        int d4 = g + j * 4;
        float4 wv = *(const float4*)(w + (size_t)lane * 64 + d4 * 4);
        Wl[d4 * 4 + 0][lane] = wv.x; Wl[d4 * 4 + 1][lane] = wv.y;
        Wl[d4 * 4 + 2][lane] = wv.z; Wl[d4 * 4 + 3][lane] = wv.w;
    }
    __syncthreads();
    int tx = tid & 15, ty = tid >> 4;
    float acc[4][4] = {};
#pragma unroll
    for (int kk = 0; kk < 64; ++kk) {
        float4 ra = *(const float4*)&F[kk][ty * 4];
        float4 rw = *(const float4*)&Wl[kk][tx * 4];
        float ar[4] = {ra.x, ra.y, ra.z, ra.w};
        float wr[4] = {rw.x, rw.y, rw.z, rw.w};
#pragma unroll
        for (int i = 0; i < 4; ++i)
#pragma unroll
            for (int j = 0; j < 4; ++j) acc[i][j] += ar[i] * wr[j];
    }
    float al = a0[l];
    const float* bia = fc_b + (l * NR + r) * 64;
#pragma unroll
    for (int i = 0; i < 4; ++i) {
        float4 o4;
        float* op = &o4.x;
#pragma unroll
        for (int j = 0; j < 4; ++j) {
            float v = acc[i][j] + bia[tx * 4 + j];
            op[j] = (v >= 0.f) ? v : al * v;
        }
        *(float4*)(diff + (size_t)br * 65536 + (size_t)(n0 + ty * 4 + i) * 64 + tx * 4) = o4;
    }
}

// ---- u[b,s,:,:] = prelu(sum_r cw*diff[b,r] + cb, a1) (float4) ----
__global__ void conv_kernel(const float* __restrict__ diff,
                            const float* __restrict__ cw, const float* __restrict__ cb,
                            const float* __restrict__ a1, float* __restrict__ u, int l) {
    int idx = blockIdx.x * 256 + threadIdx.x;
    int no4 = idx & 16383;
    int bs = idx >> 14;
    int s = bs % NR, b = bs / NR;
    const float* dbase = diff + (size_t)b * NR * 65536;
    float bias = cb[l * NR + s];
    float4 acc = make_float4(bias, bias, bias, bias);
#pragma unroll
    for (int r = 0; r < NR; ++r) {
        float w = cw[(l * NR + s) * NR + r];
        float4 dv = *(const float4*)(dbase + (size_t)r * 65536 + no4 * 4);
        acc.x += w * dv.x; acc.y += w * dv.y; acc.z += w * dv.z; acc.w += w * dv.w;
    }
    float al = a1[l];
    acc.x = acc.x >= 0.f ? acc.x : al * acc.x;
    acc.y = acc.y >= 0.f ? acc.y : al * acc.y;
    acc.z = acc.z >= 0.f ? acc.z : al * acc.z;
    acc.w = acc.w >= 0.f ? acc.w : al * acc.w;
    *(float4*)(u + (size_t)bs * 65536 + no4 * 4) = acc;
}

// ---- batched generic GEMM (BK=32, prefetch) — proven R4 version ----
struct BEnt {
    const float* A; const float* W; const float* bias; const float* alpha; float* C;
    int lda, K, Nw, ldc, w_nn, tri, trik;
};
struct BArg { BEnt e[4]; };

__global__ __launch_bounds__(256) void gemm_kernel(BArg bp) {
    BEnt E = bp.e[blockIdx.z];
    int m0 = blockIdx.y * 64, n0 = blockIdx.x * 64;
    if (n0 >= E.Nw) return;
    if (E.tri && (m0 + 63 <= n0)) return;
    int K = E.K;
    int kend = E.trik ? min(K, m0 + 64) : K;
    __shared__ float As[32][68];
    __shared__ float Ws[32][68];
    int tid = threadIdx.x;
    int c4 = tid & 7, row = tid >> 3;       // NT staging
    int n4 = tid & 15, krow = tid >> 4;     // NN staging
    int tx = tid & 15, ty = tid >> 4;
    const float* Ap = E.A; const float* Wp = E.W;
    int lda = E.lda, Nw = E.Nw;
    int wnn = E.w_nn;
    float4 pA[2], pW[2];
    auto LOAD = [&](int k0) {
#pragma unroll
        for (int j = 0; j < 2; ++j)
            pA[j] = *(const float4*)(Ap + (size_t)(m0 + row + j * 32) * lda + k0 + c4 * 4);
        if (!wnn) {
#pragma unroll
            for (int j = 0; j < 2; ++j)
                pW[j] = *(const float4*)(Wp + (size_t)(n0 + row + j * 32) * K + k0 + c4 * 4);
        } else {
#pragma unroll
            for (int j = 0; j < 2; ++j)
                pW[j] = *(const float4*)(Wp + (size_t)(k0 + krow + j * 16) * Nw + n0 + n4 * 4);
        }
    };
    float acc[4][4] = {};
    LOAD(0);
    for (int k0 = 0; k0 < kend; k0 += 32) {
        __syncthreads();
#pragma unroll
        for (int j = 0; j < 2; ++j) {
            int rr = row + j * 32;
            As[c4 * 4 + 0][rr] = pA[j].x; As[c4 * 4 + 1][rr] = pA[j].y;
            As[c4 * 4 + 2][rr] = pA[j].z; As[c4 * 4 + 3][rr] = pA[j].w;
        }
        if (!wnn) {
#pragma unroll
            for (int j = 0; j < 2; ++j) {
                int rr = row + j * 32;
                Ws[c4 * 4 + 0][rr] = pW[j].x; Ws[c4 * 4 + 1][rr] = pW[j].y;
                Ws[c4 * 4 + 2][rr] = pW[j].z; Ws[c4 * 4 + 3][rr] = pW[j].w;
            }
        } else {
#pragma unroll
            for (int j = 0; j < 2; ++j)
                *(float4*)&Ws[krow + j * 16][n4 * 4] = pW[j];
        }
        if (k0 + 32 < kend) LOAD(k0 + 32);
        __syncthreads();
#pragma unroll
        for (int kk = 0; kk < 32; ++kk) {
            float4 ra = *(const float4*)&As[kk][ty * 4];
            float4 rw = *(const float4*)&Ws[kk][tx * 4];
            float ar[4] = {ra.x, ra.y, ra.z, ra.w};
            float wr[4] = {rw.x, rw.y, rw.z, rw.w};
#pragma unroll
            for (int i = 0; i < 4; ++i)
#pragma unroll
                for (int j = 0; j < 4; ++j) acc[i][j] += ar[i] * wr[j];
        }
    }
    float al = E.alpha ? *E.alpha : 0.f;
#pragma unroll
    for (int i = 0; i < 4; ++i) {
        int m = m0 + ty * 4 + i;
        float4 o4;
        float* op = &o4.x;
#pragma unroll
        for (int j = 0; j < 4; ++j) {
            int n = n0 + tx * 4 + j;
            float v = acc[i][j];
            if (E.bias) v += E.bias[n];
            if (E.tri) v = (m > n) ? 0.4f * v : 0.f;
            if (E.alpha) v = (v >= 0.f) ? v : al * v;
            op[j] = v;
        }
        *(float4*)(E.C + (size_t)m * E.ldc + n0 + tx * 4) = o4;
    }
}

// ---- final: out[m,c] = out1[m,:] @ mlp2_w[c,:] + mlp2_b[c] ----
__global__ void final_kernel(const float* __restrict__ out1,
                             const float* __restrict__ w2, const float* __restrict__ b2,
                             float* __restrict__ out) {
    int idx = blockIdx.x * 256 + threadIdx.x;
    if (idx >= 2048 * 2) return;
    int m = idx >> 1, c = idx & 1;
    float acc = b2[c];
    const float* row = out1 + (size_t)m * 128;
#pragma unroll 8
    for (int dd = 0; dd < 128; ++dd) acc += row[dd] * w2[c * 128 + dd];
    out[idx] = acc;
}

extern "C" void kernel_launch(void* const* d_in, const int* in_sizes, int n_in,
                              void* d_out, int out_size, void* d_ws, size_t ws_size,
                              hipStream_t stream) {
    auto fp = [&](int i) { return (const float*)d_in[i]; };
    const float *x = fp(0), *a = fp(1), *T = fp(2), *theta = fp(3),
        *fc_w = fp(4), *fc_b = fp(5), *conv_w = fp(6), *conv_b = fp(7),
        *a0 = fp(8), *a1 = fp(9), *qw = fp(10), *qb = fp(11), *kw = fp(12), *kb = fp(13),
        *vw = fp(14), *vb = fp(15), *rw = fp(16), *rb = fp(17), *a_ret = fp(18),
        *l1_w = fp(19), *l1_b = fp(20), *l2_w = fp(21), *l2_b = fp(22),
        *m1w = fp(23), *m1b = fp(24), *m2w = fp(25), *m2b = fp(26), *a_mlp = fp(27);

    float* ws = (float*)d_ws;
    float* part = ws;   ws += MSPLIT * 655360;  // 21 MB; dead after reduce_fc
    float* scores = part;                        // alias: [B,N,N] 8.4 MB <= part
    float* u0 = ws;     ws += 655360;
    float* u1 = ws;     ws += 655360;
    float* skip = ws;   ws += 655360;
    float* diff = ws;   ws += 655360;
    float* q = ws;      ws += 524288;
    float* kk = ws;     ws += 524288;
    float* v = ws;      ws += 524288;
    float* ret = ws;    ws += 524288;
    float* cat = ws;    ws += 786432;           // [B,N,384] = [eta | ts]
    float* out1 = ws;   ws += 262144;           // total ~44 MB

    init_kernel<<<640, 256, 0, stream>>>(x, skip);
    for (int l = 0; l < NL; ++l) {
        const float* h = (l == 0) ? x : u0;
        float* u = (l == 0) ? u0 : u1;
        feats_kernel<<<dim3(16, 10, MSPLIT), 256, 0, stream>>>(T, theta, a, h, part, l);
        reduce_fc_kernel<<<dim3(16, 10), 256, 0, stream>>>(part, fc_w, fc_b, a0, diff, l);
        conv_kernel<<<640, 256, 0, stream>>>(diff, conv_w, conv_b, a1, u, l);
        {   // qkv + ts fused, z=4
            BArg g;
            g.e[0] = {u, qw + (size_t)l * 81920, qb + l * 256, nullptr, q, 320, 320, 256, 256, 0, 0, 0};
            g.e[1] = {u, kw + (size_t)l * 81920, kb + l * 256, nullptr, kk, 320, 320, 256, 256, 0, 0, 0};
            g.e[2] = {u, vw + (size_t)l * 81920, vb + l * 256, nullptr, v, 320, 320, 256, 256, 0, 0, 0};
            g.e[3] = {skip, l1_w + (size_t)l * 40960, l1_b + l * 128, nullptr, cat + 256, 320, 320, 128, 384, 0, 0, 0};
            gemm_kernel<<<dim3(4, 32, 4), 256, 0, stream>>>(g);
        }
        {   // scores = tri(q @ k^T), per-batch z=2, upper tiles skipped
            BArg g;
            g.e[0] = {q, kk, nullptr, nullptr, scores, 256, 256, 1024, 1024, 0, 1, 0};
            g.e[1] = {q + 262144, kk + 262144, nullptr, nullptr, scores + 1048576, 256, 256, 1024, 1024, 0, 1, 0};
            g.e[2] = g.e[0]; g.e[3] = g.e[0];
            gemm_kernel<<<dim3(16, 16, 2), 256, 0, stream>>>(g);
        }
        {   // ret = scores @ v (NN), K clamped to m0+64
            BArg g;
            g.e[0] = {scores, v, nullptr, nullptr, ret, 1024, 1024, 256, 256, 1, 0, 1};
            g.e[1] = {scores + 1048576, v + 262144, nullptr, nullptr, ret + 262144, 1024, 1024, 256, 256, 1, 0, 1};
            g.e[2] = g.e[0]; g.e[3] = g.e[0];
            gemm_kernel<<<dim3(4, 16, 2), 256, 0, stream>>>(g);
        }
        {   // eta -> cat[:,0:256], prelu(a_ret)
            BArg g;
            g.e[0] = {ret, rw + (size_t)l * 65536, rb + l * 256, a_ret + l, cat, 256, 256, 256, 384, 0, 0, 0};
            g.e[1] = g.e[0]; g.e[2] = g.e[0]; g.e[3] = g.e[0];
            gemm_kernel<<<dim3(4, 32, 1), 256, 0, stream>>>(g);
        }
        {   // skip = cat @ l2_w^T + l2_b
            BArg g;
            g.e[0] = {cat, l2_w + (size_t)l * 122880, l2_b + l * 320, nullptr, skip, 384, 384, 320, 320, 0, 0, 0};
            g.e[1] = g.e[0]; g.e[2] = g.e[0]; g.e[3] = g.e[0];
            gemm_kernel<<<dim3(5, 32, 1), 256, 0, stream>>>(g);
        }
    }
    {   // out1 = prelu(skip @ mlp1_w^T + mlp1_b, a_mlp)
        BArg g;
        g.e[0] = {skip, m1w, m1b, a_mlp, out1, 320, 320, 128, 128, 0, 0, 0};
        g.e[1] = g.e[0]; g.e[2] = g.e[0]; g.e[3] = g.e[0];
        gemm_kernel<<<dim3(2, 32, 1), 256, 0, stream>>>(g);
    }
    final_kernel<<<16, 256, 0, stream>>>(out1, m2w, m2b, (float*)d_out);
}